// Round 10
// baseline (267.499 us; speedup 1.0000x reference)
//
#include <hip/hip_runtime.h>
#include <hip/hip_bf16.h>
#include <math.h>

#define DEV __device__ __forceinline__

using bf16x8 = __attribute__((ext_vector_type(8))) short;
using f32x4  = __attribute__((ext_vector_type(4))) float;

static constexpr int Bb = 8, Nn = 1024, Dd = 512, Hh = 8, DHd = 64, FFd = 2048;
static constexpr int Mrows = Bb * Nn; // 8192

DEV short f2bf(float f) {
  union { float f; unsigned u; } v; v.f = f;
  unsigned r = v.u + 0x7fffu + ((v.u >> 16) & 1u);
  return (short)(r >> 16);
}

DEV f32x4 mfma16(bf16x8 a, bf16x8 b, f32x4 c) {
  return __builtin_amdgcn_mfma_f32_16x16x32_bf16(a, b, c, 0, 0, 0);
}

// counted vmcnt wait (compile-time literal)
template<int N> DEV void wait_vmcnt() {
  if constexpr (N == 0)      asm volatile("s_waitcnt vmcnt(0)" ::: "memory");
  else if constexpr (N == 3) asm volatile("s_waitcnt vmcnt(3)" ::: "memory");
  else if constexpr (N == 6) asm volatile("s_waitcnt vmcnt(6)" ::: "memory");
  else static_assert(N == 0 || N == 3 || N == 6, "unsupported vmcnt");
}

// swizzle64 layout for all bf16 operand buffers:
// element (row r, col k, leading-dim ld) lives at
//   (r>>6)*64*ld + (k>>3)*512 + (r&63)*8 + (k&7)
// -> any 64-row x 8-col octet panel is 1KB contiguous (per-wave gload16 unit),
//    and plane-major LDS tiles stage from it with perfectly coalesced reads.
DEV size_t swz(int r, int k, int ld) {
  return (size_t)(r >> 6) * 64 * ld + (size_t)(k >> 3) * 512
       + (size_t)((r & 63) * 8 + (k & 7));
}

// async global->LDS, 16B per lane. LDS dest is wave-uniform base + lane*16.
DEV void gload16(const void* g, void* l) {
  __builtin_amdgcn_global_load_lds(
      (const __attribute__((address_space(1))) void*)g,
      (__attribute__((address_space(3))) void*)l, 16, 0, 0);
}

// gelu_new(g) = g * sigmoid(2 * 0.79788456 * (g + 0.044715 g^3))
DEV float gelu_fast(float g) {
  float u2 = 1.5957691216057308f * (g + 0.044715f * g * g * g);
  return g / (1.0f + __expf(-u2));
}

// 2-D per-XCD chunk swizzle.
DEV void xcd_tile(int gx, int gy, int& trow, int& tcol) {
  int wg = blockIdx.y * gx + blockIdx.x;
  int xcd = wg & 7, idx = wg >> 3;
  int XC = (gx >= 16) ? 2 : 1, XR = 8 / XC;
  int lcx = gx / XC, lcy = gy / XR;
  trow = (xcd / XC) * lcy + idx / lcx;
  tcol = (xcd % XC) * lcx + idx % lcx;
}

// ---------------- batched transpose f32 [K][N] -> bf16 swz[N][K] ------------
struct TJob { const float* src; short* dst; };
struct TJobs { TJob j[4]; };
__global__ __launch_bounds__(256)
void k_transpose_bf16(TJobs jobs, int K, int N) {
  const float* W = jobs.j[blockIdx.z].src;
  short* WT = jobs.j[blockIdx.z].dst;
  __shared__ float tile[32][33];
  int nb = blockIdx.x * 32, kb = blockIdx.y * 32;
  int tx = threadIdx.x & 31, ty = threadIdx.x >> 5;
  #pragma unroll
  for (int i = ty; i < 32; i += 8)
    tile[i][tx] = W[(size_t)(kb + i) * N + nb + tx];
  __syncthreads();
  #pragma unroll
  for (int i = ty; i < 32; i += 8)
    WT[swz(nb + i, kb + tx, K)] = f2bf(tile[tx][i]);
}

// ---------------- mask precompute: allowC[b][n] = (train|batch)!=0 ----------
__global__ __launch_bounds__(256)
void k_mask(const int* __restrict__ train, const int* __restrict__ batch,
            char* __restrict__ allowC) {
  int i = blockIdx.x * 256 + threadIdx.x;
  allowC[i] = ((train[i] | batch[i]) != 0) ? 1 : 0;
}

// ---------------- layernorm: one row per WAVE, no barriers ------------------
template<bool WRITE_RAW>
__global__ __launch_bounds__(256)
void k_layernorm(const float* __restrict__ X, const float* __restrict__ sc,
                 const float* __restrict__ bi, short* __restrict__ out,
                 short* __restrict__ raw) {
  int w = threadIdx.x >> 6, lane = threadIdx.x & 63;
  int row = blockIdx.x * 4 + w;
  const float* x = X + (size_t)row * Dd + lane * 8;
  f32x4 a = *(const f32x4*)x;
  f32x4 b = *(const f32x4*)(x + 4);
  float p = a[0] + a[1] + a[2] + a[3] + b[0] + b[1] + b[2] + b[3];
  #pragma unroll
  for (int off = 1; off < 64; off <<= 1) p += __shfl_xor(p, off);
  float mean = p * (1.0f / Dd);
  float d[8];
  #pragma unroll
  for (int j = 0; j < 4; j++) { d[j] = a[j] - mean; d[4 + j] = b[j] - mean; }
  float q = 0.0f;
  #pragma unroll
  for (int j = 0; j < 8; j++) q += d[j] * d[j];
  #pragma unroll
  for (int off = 1; off < 64; off <<= 1) q += __shfl_xor(q, off);
  float rs = rsqrtf(q * (1.0f / Dd) + 1e-12f);
  int c0 = lane * 8;
  f32x4 s0 = *(const f32x4*)(sc + c0), s1 = *(const f32x4*)(sc + c0 + 4);
  f32x4 b0 = *(const f32x4*)(bi + c0), b1 = *(const f32x4*)(bi + c0 + 4);
  bf16x8 o;
  #pragma unroll
  for (int j = 0; j < 4; j++) {
    o[j]     = f2bf(d[j] * rs * s0[j] + b0[j]);
    o[4 + j] = f2bf(d[4 + j] * rs * s1[j] + b1[j]);
  }
  *(bf16x8*)(out + swz(row, c0, Dd)) = o;
  if (WRITE_RAW) {
    bf16x8 rv;
    #pragma unroll
    for (int j = 0; j < 4; j++) { rv[j] = f2bf(a[j]); rv[4 + j] = f2bf(b[j]); }
    *(bf16x8*)(raw + swz(row, c0, Dd)) = rv;
  }
}

// ---------------- LDS-staged bf16 MFMA GEMM: C = A[M][K] @ BT[N][K]^T -------
// A/BT in swz layout. 128 x BN tile, BK=32, 4 waves.
// 3-buffer pipeline, 2 tiles in flight, counted vmcnt (T4): the end-of-iter
// wait leaves the newest tile's loads outstanding across the barrier.
// BIASM: 0 = none, 1 = bias[col], 2 = bias[row].
template<int BN, int BIASM, bool RES, bool WF, bool WB>
__global__ __launch_bounds__(256)
void k_gemm128(const short* __restrict__ A, const short* __restrict__ BT,
               const float* __restrict__ bias, const float* __restrict__ res,
               float* __restrict__ outF, short* __restrict__ outB,
               int M, int N, int K) {
  constexpr int FN = BN / 32;        // frag cols per wave
  constexpr int LOADS = 2 + BN / 64; // per-thread gloads per K-tile
  __shared__ short lA[3][128 * 32];
  __shared__ short lB[3][BN * 32];
  int tid = threadIdx.x, w = tid >> 6, lane = tid & 63;
  int lr = lane & 15, lg = lane >> 4;
  int wr = w >> 1, wc = w & 1;
  int trow, tcol;
  xcd_tile(gridDim.x, gridDim.y, trow, tcol);
  int row0 = trow * 128, col0 = tcol * BN;
  f32x4 acc[4][FN] = {};

  auto stage = [&](int buf, int k0) {
    #pragma unroll
    for (int i = 0; i < 2; i++) {            // A: 8 chunks of 1KB
      int c = i * 4 + w;
      gload16(A + swz(row0 + (c & 1) * 64 + lane, k0 + (c >> 1) * 8, K),
              &lA[buf][c * 512]);
    }
    #pragma unroll
    for (int i = 0; i < BN / 64; i++) {      // B: BN/16 chunks
      int c = i * 4 + w;
      if (BN == 128)
        gload16(BT + swz(col0 + (c & 1) * 64 + lane, k0 + (c >> 1) * 8, K),
                &lB[buf][c * 512]);
      else
        gload16(BT + swz(col0 + lane, k0 + c * 8, K), &lB[buf][c * 512]);
    }
  };

  int nt = K / 32;
  stage(0, 0);
  stage(1, 32);
  wait_vmcnt<LOADS>();                 // tile 0 landed; tile 1 in flight
  __builtin_amdgcn_s_barrier();
  __builtin_amdgcn_sched_barrier(0);

  for (int t = 0; t < nt; t++) {
    int b = t % 3;
    if (t + 2 < nt) stage((t + 2) % 3, (t + 2) * 32);
    bf16x8 af[4];
    #pragma unroll
    for (int m = 0; m < 4; m++)
      af[m] = *(const bf16x8*)&lA[b][lg * 1024 + (wr * 64 + m * 16 + lr) * 8];
    #pragma unroll
    for (int n = 0; n < FN; n++) {
      bf16x8 bfr = *(const bf16x8*)&lB[b][lg * (BN * 8) + (wc * (BN / 2) + n * 16 + lr) * 8];
      #pragma unroll
      for (int m = 0; m < 4; m++)
        acc[m][n] = mfma16(af[m], bfr, acc[m][n]);
    }
    __builtin_amdgcn_sched_barrier(0);
    if (t + 2 < nt) wait_vmcnt<LOADS>(); else wait_vmcnt<0>();
    __builtin_amdgcn_s_barrier();
    __builtin_amdgcn_sched_barrier(0);
  }

  #pragma unroll
  for (int n = 0; n < FN; n++) {
    int col = col0 + wc * (BN / 2) + n * 16 + lr;
    float bv = (BIASM == 1) ? bias[col] : 0.0f;
    #pragma unroll
    for (int m = 0; m < 4; m++) {
      #pragma unroll
      for (int r = 0; r < 4; r++) {
        int rowg = row0 + wr * 64 + m * 16 + lg * 4 + r;
        float vv = acc[m][n][r] + bv;
        if (BIASM == 2) vv += bias[rowg];
        if (RES) vv += res[(size_t)rowg * N + col];
        if (WF) outF[(size_t)rowg * N + col] = vv;
        if (WB) outB[swz(rowg, col, N)] = f2bf(vv);
      }
    }
  }
}

// ---------------- fused GEGLU: out = gelu(A@B0^T) * (A@B1^T), BN=128 --------
__global__ __launch_bounds__(256)
void k_geglu128(const short* __restrict__ A, const short* __restrict__ BT0,
                const short* __restrict__ BT1, short* __restrict__ outB,
                int M, int N, int K) {
  __shared__ short lA[3][128 * 32];
  __shared__ short lB0[3][128 * 32];
  __shared__ short lB1[3][128 * 32];
  int tid = threadIdx.x, w = tid >> 6, lane = tid & 63;
  int lr = lane & 15, lg = lane >> 4;
  int wr = w >> 1, wc = w & 1;
  int trow, tcol;
  xcd_tile(gridDim.x, gridDim.y, trow, tcol);
  int row0 = trow * 128, col0 = tcol * 128;
  f32x4 acc0[4][4] = {}, acc1[4][4] = {};

  auto stage = [&](int buf, int k0) {
    #pragma unroll
    for (int i = 0; i < 2; i++) {
      int c = i * 4 + w;
      int rsub = (c & 1) * 64 + lane;
      int kk = k0 + (c >> 1) * 8;
      gload16(A   + swz(row0 + rsub, kk, K), &lA[buf][c * 512]);
      gload16(BT0 + swz(col0 + rsub, kk, K), &lB0[buf][c * 512]);
      gload16(BT1 + swz(col0 + rsub, kk, K), &lB1[buf][c * 512]);
    }
  };

  int nt = K / 32;
  stage(0, 0);
  stage(1, 32);
  wait_vmcnt<6>();
  __builtin_amdgcn_s_barrier();
  __builtin_amdgcn_sched_barrier(0);

  for (int t = 0; t < nt; t++) {
    int b = t % 3;
    if (t + 2 < nt) stage((t + 2) % 3, (t + 2) * 32);
    bf16x8 af[4];
    #pragma unroll
    for (int m = 0; m < 4; m++)
      af[m] = *(const bf16x8*)&lA[b][lg * 1024 + (wr * 64 + m * 16 + lr) * 8];
    #pragma unroll
    for (int n = 0; n < 4; n++) {
      bf16x8 b0 = *(const bf16x8*)&lB0[b][lg * 1024 + (wc * 64 + n * 16 + lr) * 8];
      #pragma unroll
      for (int m = 0; m < 4; m++)
        acc0[m][n] = mfma16(af[m], b0, acc0[m][n]);
      bf16x8 b1 = *(const bf16x8*)&lB1[b][lg * 1024 + (wc * 64 + n * 16 + lr) * 8];
      #pragma unroll
      for (int m = 0; m < 4; m++)
        acc1[m][n] = mfma16(af[m], b1, acc1[m][n]);
    }
    __builtin_amdgcn_sched_barrier(0);
    if (t + 2 < nt) wait_vmcnt<6>(); else wait_vmcnt<0>();
    __builtin_amdgcn_s_barrier();
    __builtin_amdgcn_sched_barrier(0);
  }

  #pragma unroll
  for (int n = 0; n < 4; n++) {
    int col = col0 + wc * 64 + n * 16 + lr;
    #pragma unroll
    for (int m = 0; m < 4; m++) {
      #pragma unroll
      for (int r = 0; r < 4; r++) {
        int rowg = row0 + wr * 64 + m * 16 + lg * 4 + r;
        float g  = acc0[m][n][r];
        float x2 = acc1[m][n][r];
        outB[swz(rowg, col, N)] = f2bf(gelu_fast(g) * x2);
      }
    }
  }
}

// ---------------- flash attention, barrier-free, pipelined ------------------
// Qbf/Kbf swz over [Mrows][Dd]; VT swz over [Dd][Mrows].
__global__ __launch_bounds__(256, 2)
void k_attention(const short* __restrict__ Qbf, const short* __restrict__ Kbf,
                 const short* __restrict__ VT, const char* __restrict__ allowC,
                 short* __restrict__ Obf) {
  __shared__ __align__(16) short Plds[4][32][72];  // per-wave P: [q][key]
  __shared__ char allow[Nn];
  int bid = blockIdx.x;
  int h = bid & 7, b = (bid >> 3) & 7, qt = bid >> 6;
  int tid = threadIdx.x, w = tid >> 6, lane = tid & 63, lr = lane & 15, lg = lane >> 4;
  int q0 = qt * 128 + w * 32;   // this wave's first q row

  ((int*)allow)[tid] = ((const int*)(allowC + b * Nn))[tid];
  __syncthreads();

  // Q fragments: 2 sub-tiles of 16 rows
  bf16x8 aq[2][2];
  #pragma unroll
  for (int qi = 0; qi < 2; qi++) {
    #pragma unroll
    for (int j = 0; j < 2; j++)
      aq[qi][j] = *(const bf16x8*)(Qbf + swz(b * Nn + q0 + qi * 16 + lr,
                                             h * 64 + j * 32 + lg * 8, Dd));
  }
  f32x4 acco[2][4] = {};
  float m_run[2][4], l_run[2][4];
  #pragma unroll
  for (int qi = 0; qi < 2; qi++)
  #pragma unroll
  for (int r = 0; r < 4; r++) { m_run[qi][r] = -1e30f; l_run[qi][r] = 0.0f; }
  const float scale = 0.044194173824159216f; // 1/sqrt(512)

  auto loadK = [&](bf16x8 (&kf)[4][2], int kb) {
    #pragma unroll
    for (int sub = 0; sub < 4; sub++)
    #pragma unroll
    for (int j = 0; j < 2; j++)
      kf[sub][j] = *(const bf16x8*)(Kbf + swz(b * Nn + kb + sub * 16 + lr,
                                              h * 64 + j * 32 + lg * 8, Dd));
  };

  auto process = [&](bf16x8 (&kf)[4][2], int kb, bf16x8 (&kfn)[4][2], int kbn) {
    loadK(kfn, kbn);                       // prefetch next K tile
    bf16x8 vb[2][4];                       // V^T frags for THIS tile, issued early
    #pragma unroll
    for (int ks = 0; ks < 2; ks++)
    #pragma unroll
    for (int t = 0; t < 4; t++)
      vb[ks][t] = *(const bf16x8*)(VT + swz(h * 64 + t * 16 + lr,
                                            b * Nn + kb + ks * 32 + lg * 8, Mrows));
    // S = Q K^T
    f32x4 accs[2][4] = {};
    #pragma unroll
    for (int sub = 0; sub < 4; sub++) {
      #pragma unroll
      for (int qi = 0; qi < 2; qi++) {
        accs[qi][sub] = mfma16(aq[qi][0], kf[sub][0], accs[qi][sub]);
        accs[qi][sub] = mfma16(aq[qi][1], kf[sub][1], accs[qi][sub]);
      }
    }
    #pragma unroll
    for (int qi = 0; qi < 2; qi++) {
      float sv[4][4];
      #pragma unroll
      for (int sub = 0; sub < 4; sub++) {
        int key = kb + sub * 16 + lr;
        int allowed = allow[key];
        #pragma unroll
        for (int r = 0; r < 4; r++) {
          int qrow = q0 + qi * 16 + lg * 4 + r;
          float s = accs[qi][sub][r] * scale;
          sv[sub][r] = (allowed || key == qrow) ? s : -1e30f;
        }
      }
      #pragma unroll
      for (int r = 0; r < 4; r++) {
        float m = fmaxf(fmaxf(sv[0][r], sv[1][r]), fmaxf(sv[2][r], sv[3][r]));
        #pragma unroll
        for (int off = 1; off < 16; off <<= 1) m = fmaxf(m, __shfl_xor(m, off));
        float mtot = fmaxf(m_run[qi][r], m);
        float alpha = __expf(m_run[qi][r] - mtot);
        float lsum = 0.0f;
        #pragma unroll
        for (int sub = 0; sub < 4; sub++) {
          sv[sub][r] = __expf(sv[sub][r] - mtot);
          lsum += sv[sub][r];
        }
        l_run[qi][r] = l_run[qi][r] * alpha + lsum;  // per-lane partial sum
        m_run[qi][r] = mtot;
        #pragma unroll
        for (int t = 0; t < 4; t++) acco[qi][t][r] *= alpha;
      }
      #pragma unroll
      for (int sub = 0; sub < 4; sub++)
      #pragma unroll
      for (int r = 0; r < 4; r++)
        Plds[w][qi * 16 + lg * 4 + r][sub * 16 + lr] = f2bf(sv[sub][r]);
    }
    // O += P @ V
    #pragma unroll
    for (int ks = 0; ks < 2; ks++) {
      bf16x8 pa0 = *(const bf16x8*)(&Plds[w][lr][ks * 32 + lg * 8]);
      bf16x8 pa1 = *(const bf16x8*)(&Plds[w][16 + lr][ks * 32 + lg * 8]);
      #pragma unroll
      for (int t = 0; t < 4; t++) {
        acco[0][t] = mfma16(pa0, vb[ks][t], acco[0][t]);
        acco[1][t] = mfma16(pa1, vb[ks][t], acco[1][t]);
      }
    }
  };

  bf16x8 kfA[4][2], kfB[4][2];
  loadK(kfA, 0);
  for (int kb = 0; kb < Nn; kb += 128) {
    int n1 = kb + 64;
    int n2 = (kb + 128 < Nn) ? (kb + 128) : 0;
    process(kfA, kb, kfB, n1);
    process(kfB, n1, kfA, n2);
  }

  // epilogue: reduce l across the 16-lane group, divide, write bf16 O (swz)
  #pragma unroll
  for (int qi = 0; qi < 2; qi++)
  #pragma unroll
  for (int r = 0; r < 4; r++) {
    float lsum = l_run[qi][r];
    #pragma unroll
    for (int off = 1; off < 16; off <<= 1) lsum += __shfl_xor(lsum, off);
    l_run[qi][r] = lsum;
  }
  #pragma unroll
  for (int qi = 0; qi < 2; qi++)
  #pragma unroll
  for (int t = 0; t < 4; t++)
  #pragma unroll
  for (int r = 0; r < 4; r++) {
    int q = b * Nn + q0 + qi * 16 + lg * 4 + r;
    Obf[swz(q, h * 64 + t * 16 + lr, Dd)] = f2bf(acco[qi][t][r] / l_run[qi][r]);
  }
}

// ---------------------------------------------------------------------------
extern "C" void kernel_launch(void* const* d_in, const int* in_sizes, int n_in,
                              void* d_out, int out_size, void* d_ws, size_t ws_size,
                              hipStream_t stream) {
  const float* X    = (const float*)d_in[0];
  const int*   train= (const int*)d_in[1];
  const int*   batch= (const int*)d_in[2];
  const float* Wq   = (const float*)d_in[3];
  const float* bq   = (const float*)d_in[4];
  const float* Wk   = (const float*)d_in[5];
  const float* bk   = (const float*)d_in[6];
  const float* Wv   = (const float*)d_in[7];
  const float* bv   = (const float*)d_in[8];
  const float* Wmix = (const float*)d_in[9];
  const float* bmix = (const float*)d_in[10];
  const float* ln0s = (const float*)d_in[11];
  const float* ln0b = (const float*)d_in[12];
  const float* ln1s = (const float*)d_in[13];
  const float* ln1b = (const float*)d_in[14];
  const float* wi0  = (const float*)d_in[15];
  const float* wi1  = (const float*)d_in[16];
  const float* wo   = (const float*)d_in[17];
  float* out = (float*)d_out;

  char* ws = (char*)d_ws;
  size_t off = 0;
  auto alloc = [&](size_t bytes) {
    off = (off + 255) & ~(size_t)255;
    void* p = ws + off; off += bytes; return p;
  };
  short* Xbf   = (short*)alloc((size_t)Mrows * Dd * 2);
  short* Xnbf  = (short*)alloc((size_t)Mrows * Dd * 2);
  short* Qbf   = (short*)alloc((size_t)Mrows * Dd * 2);
  short* Kbf   = (short*)alloc((size_t)Mrows * Dd * 2);
  short* VTg   = (short*)alloc((size_t)Dd * Mrows * 2);   // V^T swz [Dd][Mrows]
  short* Obf   = (short*)alloc((size_t)Mrows * Dd * 2);
  short* x1bf  = (short*)alloc((size_t)Mrows * Dd * 2);
  short* FFbf  = (short*)alloc((size_t)Mrows * FFd * 2);
  short* WqT   = (short*)alloc((size_t)Dd * Dd * 2);
  short* WkT   = (short*)alloc((size_t)Dd * Dd * 2);
  short* WvT   = (short*)alloc((size_t)Dd * Dd * 2);
  short* WmixT = (short*)alloc((size_t)Dd * Dd * 2);
  short* wi0T  = (short*)alloc((size_t)FFd * Dd * 2);
  short* wi1T  = (short*)alloc((size_t)FFd * Dd * 2);
  short* woT   = (short*)alloc((size_t)Dd * FFd * 2);
  float* Qf    = (float*)alloc((size_t)Mrows * Dd * 4);
  float* Hcf   = (float*)alloc((size_t)Mrows * Dd * 4);
  char*  allowC= (char*)alloc((size_t)Mrows);

  dim3 blk(256);
  // weight transposes to bf16 swz[N][K] (batched)
  TJobs tj4; tj4.j[0] = {Wq, WqT}; tj4.j[1] = {Wk, WkT};
  tj4.j[2] = {Wv, WvT}; tj4.j[3] = {Wmix, WmixT};
  k_transpose_bf16<<<dim3(Dd / 32, Dd / 32, 4), blk, 0, stream>>>(tj4, Dd, Dd);
  TJobs tj2; tj2.j[0] = {wi0, wi0T}; tj2.j[1] = {wi1, wi1T};
  tj2.j[2] = {wi0, wi0T}; tj2.j[3] = {wi1, wi1T};
  k_transpose_bf16<<<dim3(FFd / 32, Dd / 32, 2), blk, 0, stream>>>(tj2, Dd, FFd);
  TJobs tj1; tj1.j[0] = {wo, woT}; tj1.j[1] = {wo, woT};
  tj1.j[2] = {wo, woT}; tj1.j[3] = {wo, woT};
  k_transpose_bf16<<<dim3(Dd / 32, FFd / 32, 1), blk, 0, stream>>>(tj1, FFd, Dd);

  // mask
  k_mask<<<Mrows / 256, blk, 0, stream>>>(train, batch, allowC);

  // LN0 (writes Xn bf16 and raw X bf16) -- one row per wave
  k_layernorm<true><<<Mrows / 4, blk, 0, stream>>>(X, ln0s, ln0b, Xnbf, Xbf);

  // Q (f32 for residual + bf16 for attention), K
  k_gemm128<64, 1, false, true,  true ><<<dim3(Dd / 64, Mrows / 128), blk, 0, stream>>>(
      Xnbf, WqT, bq, nullptr, Qf, Qbf, Mrows, Dd, Dd);
  k_gemm128<64, 1, false, false, true ><<<dim3(Dd / 64, Mrows / 128), blk, 0, stream>>>(
      Xbf, WkT, bk, nullptr, nullptr, Kbf, Mrows, Dd, Dd);
  // V^T = WvT @ Xbf^T  (bias indexed by output ROW = V column)
  k_gemm128<64, 2, false, false, true ><<<dim3(Mrows / 64, Dd / 128), blk, 0, stream>>>(
      WvT, Xbf, bv, nullptr, nullptr, VTg, Dd, Mrows, Dd);

  // attention (barrier-free, 128 q-rows per block, XCD-pinned per head)
  k_attention<<<Bb * Hh * (Nn / 128), blk, 0, stream>>>(Qbf, Kbf, VTg, allowC, Obf);

  // Hc = O @ Wmix + bmix + Q
  k_gemm128<64, 1, true, true, false><<<dim3(Dd / 64, Mrows / 128), blk, 0, stream>>>(
      Obf, WmixT, bmix, Qf, Hcf, nullptr, Mrows, Dd, Dd);

  // LN1
  k_layernorm<false><<<Mrows / 4, blk, 0, stream>>>(Hcf, ln1s, ln1b, x1bf, nullptr);

  // FF: gelu(x1@wi0) * (x1@wi1) fused, 128x128 tiles
  k_geglu128<<<dim3(FFd / 128, Mrows / 128), blk, 0, stream>>>(
      x1bf, wi0T, wi1T, FFbf, Mrows, FFd, Dd);

  // out = Hc + FF @ wo
  k_gemm128<64, 0, true, true, false><<<dim3(Dd / 64, Mrows / 128), blk, 0, stream>>>(
      FFbf, woT, nullptr, Hcf, out, nullptr, Mrows, Dd, FFd);
}

// Round 11
// 246.568 us; speedup vs baseline: 1.0849x; 1.0849x over previous
//
#include <hip/hip_runtime.h>
#include <hip/hip_bf16.h>
#include <math.h>

#define DEV __device__ __forceinline__

using bf16x8 = __attribute__((ext_vector_type(8))) short;
using f32x4  = __attribute__((ext_vector_type(4))) float;

static constexpr int Bb = 8, Nn = 1024, Dd = 512, Hh = 8, DHd = 64, FFd = 2048;
static constexpr int Mrows = Bb * Nn; // 8192

DEV short f2bf(float f) {
  union { float f; unsigned u; } v; v.f = f;
  unsigned r = v.u + 0x7fffu + ((v.u >> 16) & 1u);
  return (short)(r >> 16);
}
DEV float bf2f(short s) {
  union { unsigned u; float f; } v; v.u = ((unsigned)(unsigned short)s) << 16;
  return v.f;
}

DEV f32x4 mfma16(bf16x8 a, bf16x8 b, f32x4 c) {
  return __builtin_amdgcn_mfma_f32_16x16x32_bf16(a, b, c, 0, 0, 0);
}

// swizzle64 layout for all bf16 operand buffers:
// element (row r, col k, leading-dim ld) lives at
//   (r>>6)*64*ld + (k>>3)*512 + (r&63)*8 + (k&7)
// -> any 64-row x 8-col octet panel is 1KB contiguous (per-wave gload16 unit),
//    and plane-major LDS tiles stage from it with perfectly coalesced reads.
DEV size_t swz(int r, int k, int ld) {
  return (size_t)(r >> 6) * 64 * ld + (size_t)(k >> 3) * 512
       + (size_t)((r & 63) * 8 + (k & 7));
}

// async global->LDS, 16B per lane. LDS dest is wave-uniform base + lane*16.
DEV void gload16(const void* g, void* l) {
  __builtin_amdgcn_global_load_lds(
      (const __attribute__((address_space(1))) void*)g,
      (__attribute__((address_space(3))) void*)l, 16, 0, 0);
}

// gelu_new(g) = g * sigmoid(2 * 0.79788456 * (g + 0.044715 g^3))
DEV float gelu_fast(float g) {
  float u2 = 1.5957691216057308f * (g + 0.044715f * g * g * g);
  return g / (1.0f + __expf(-u2));
}

// 2-D per-XCD chunk swizzle.
DEV void xcd_tile(int gx, int gy, int& trow, int& tcol) {
  int wg = blockIdx.y * gx + blockIdx.x;
  int xcd = wg & 7, idx = wg >> 3;
  int XC = (gx >= 16) ? 2 : 1, XR = 8 / XC;
  int lcx = gx / XC, lcy = gy / XR;
  trow = (xcd / XC) * lcy + idx / lcx;
  tcol = (xcd % XC) * lcx + idx % lcx;
}

// ---------------- batched transpose f32 [K][N] -> bf16 swz[N][K] ------------
struct TJob { const float* src; short* dst; };
struct TJobs { TJob j[4]; };
__global__ __launch_bounds__(256)
void k_transpose_bf16(TJobs jobs, int K, int N) {
  const float* W = jobs.j[blockIdx.z].src;
  short* WT = jobs.j[blockIdx.z].dst;
  __shared__ float tile[32][33];
  int nb = blockIdx.x * 32, kb = blockIdx.y * 32;
  int tx = threadIdx.x & 31, ty = threadIdx.x >> 5;
  #pragma unroll
  for (int i = ty; i < 32; i += 8)
    tile[i][tx] = W[(size_t)(kb + i) * N + nb + tx];
  __syncthreads();
  #pragma unroll
  for (int i = ty; i < 32; i += 8)
    WT[swz(nb + i, kb + tx, K)] = f2bf(tile[tx][i]);
}

// ---------------- mask precompute: allowC[b][n] = (train|batch)!=0 ----------
__global__ __launch_bounds__(256)
void k_mask(const int* __restrict__ train, const int* __restrict__ batch,
            char* __restrict__ allowC) {
  int i = blockIdx.x * 256 + threadIdx.x;
  allowC[i] = ((train[i] | batch[i]) != 0) ? 1 : 0;
}

// ---------------- layernorm: one row per WAVE, no barriers ------------------
template<bool WRITE_RAW>
__global__ __launch_bounds__(256)
void k_layernorm(const float* __restrict__ X, const float* __restrict__ sc,
                 const float* __restrict__ bi, short* __restrict__ out,
                 short* __restrict__ raw) {
  int w = threadIdx.x >> 6, lane = threadIdx.x & 63;
  int row = blockIdx.x * 4 + w;
  const float* x = X + (size_t)row * Dd + lane * 8;
  f32x4 a = *(const f32x4*)x;
  f32x4 b = *(const f32x4*)(x + 4);
  float p = a[0] + a[1] + a[2] + a[3] + b[0] + b[1] + b[2] + b[3];
  #pragma unroll
  for (int off = 1; off < 64; off <<= 1) p += __shfl_xor(p, off);
  float mean = p * (1.0f / Dd);
  float d[8];
  #pragma unroll
  for (int j = 0; j < 4; j++) { d[j] = a[j] - mean; d[4 + j] = b[j] - mean; }
  float q = 0.0f;
  #pragma unroll
  for (int j = 0; j < 8; j++) q += d[j] * d[j];
  #pragma unroll
  for (int off = 1; off < 64; off <<= 1) q += __shfl_xor(q, off);
  float rs = rsqrtf(q * (1.0f / Dd) + 1e-12f);
  int c0 = lane * 8;
  f32x4 s0 = *(const f32x4*)(sc + c0), s1 = *(const f32x4*)(sc + c0 + 4);
  f32x4 b0 = *(const f32x4*)(bi + c0), b1 = *(const f32x4*)(bi + c0 + 4);
  bf16x8 o;
  #pragma unroll
  for (int j = 0; j < 4; j++) {
    o[j]     = f2bf(d[j] * rs * s0[j] + b0[j]);
    o[4 + j] = f2bf(d[4 + j] * rs * s1[j] + b1[j]);
  }
  *(bf16x8*)(out + swz(row, c0, Dd)) = o;
  if (WRITE_RAW) {
    bf16x8 rv;
    #pragma unroll
    for (int j = 0; j < 4; j++) { rv[j] = f2bf(a[j]); rv[4 + j] = f2bf(b[j]); }
    *(bf16x8*)(raw + swz(row, c0, Dd)) = rv;
  }
}

// ---------------- LDS-staged bf16 MFMA GEMM: C = A[M][K] @ BT[N][K]^T -------
// A/BT in swz layout. 128 x BN tile, BK=32, 4 waves, 2-buf stage-ahead.
// Plane-major LDS [k-octet][row][8]: conflict-free reads, coalesced staging.
// __launch_bounds__(256,4): cap VGPR at 128 -> 4 waves/SIMD residency.
// BIASM: 0 none, 1 bias[col], 2 bias[row].  EPI: 0 none, 1 gelu, 2 mul-by-G.
template<int BN, int BIASM, bool RES, bool WF, bool WB, int EPI>
__global__ __launch_bounds__(256, 4)
void k_gemm128(const short* __restrict__ A, const short* __restrict__ BT,
               const float* __restrict__ bias, const float* __restrict__ res,
               const short* __restrict__ gpre,
               float* __restrict__ outF, short* __restrict__ outB,
               int M, int N, int K) {
  constexpr int FN = BN / 32;   // frag cols per wave
  __shared__ short lA[2][128 * 32];
  __shared__ short lB[2][BN * 32];
  int tid = threadIdx.x, w = tid >> 6, lane = tid & 63;
  int lr = lane & 15, lg = lane >> 4;
  int wr = w >> 1, wc = w & 1;
  int trow, tcol;
  xcd_tile(gridDim.x, gridDim.y, trow, tcol);
  int row0 = trow * 128, col0 = tcol * BN;
  f32x4 acc[4][FN] = {};

  auto stage = [&](int buf, int k0) {
    #pragma unroll
    for (int i = 0; i < 2; i++) {            // A: 8 chunks of 1KB
      int c = i * 4 + w;
      gload16(A + swz(row0 + (c & 1) * 64 + lane, k0 + (c >> 1) * 8, K),
              &lA[buf][c * 512]);
    }
    #pragma unroll
    for (int i = 0; i < BN / 64; i++) {      // B: BN/16 chunks
      int c = i * 4 + w;
      if (BN == 128)
        gload16(BT + swz(col0 + (c & 1) * 64 + lane, k0 + (c >> 1) * 8, K),
                &lB[buf][c * 512]);
      else
        gload16(BT + swz(col0 + lane, k0 + c * 8, K), &lB[buf][c * 512]);
    }
  };

  stage(0, 0);
  __syncthreads();
  int nt = K / 32, buf = 0;
  for (int t = 0; t < nt; t++) {
    if (t + 1 < nt) stage(buf ^ 1, (t + 1) * 32);
    bf16x8 af[4];
    #pragma unroll
    for (int m = 0; m < 4; m++)
      af[m] = *(const bf16x8*)&lA[buf][lg * 1024 + (wr * 64 + m * 16 + lr) * 8];
    #pragma unroll
    for (int n = 0; n < FN; n++) {
      bf16x8 bfr = *(const bf16x8*)&lB[buf][lg * (BN * 8) + (wc * (BN / 2) + n * 16 + lr) * 8];
      #pragma unroll
      for (int m = 0; m < 4; m++)
        acc[m][n] = mfma16(af[m], bfr, acc[m][n]);
    }
    __syncthreads();
    buf ^= 1;
  }

  #pragma unroll
  for (int n = 0; n < FN; n++) {
    int col = col0 + wc * (BN / 2) + n * 16 + lr;
    float bv = (BIASM == 1) ? bias[col] : 0.0f;
    #pragma unroll
    for (int m = 0; m < 4; m++) {
      #pragma unroll
      for (int r = 0; r < 4; r++) {
        int rowg = row0 + wr * 64 + m * 16 + lg * 4 + r;
        float vv = acc[m][n][r] + bv;
        if (BIASM == 2) vv += bias[rowg];
        if (RES) vv += res[(size_t)rowg * N + col];
        if (EPI == 1) vv = gelu_fast(vv);
        if (EPI == 2) vv *= bf2f(gpre[swz(rowg, col, N)]);
        if (WF) outF[(size_t)rowg * N + col] = vv;
        if (WB) outB[swz(rowg, col, N)] = f2bf(vv);
      }
    }
  }
}

// ---------------- flash attention, barrier-free, pipelined ------------------
// Qbf/Kbf swz over [Mrows][Dd]; VT swz over [Dd][Mrows].
__global__ __launch_bounds__(256, 2)
void k_attention(const short* __restrict__ Qbf, const short* __restrict__ Kbf,
                 const short* __restrict__ VT, const char* __restrict__ allowC,
                 short* __restrict__ Obf) {
  __shared__ __align__(16) short Plds[4][32][72];  // per-wave P: [q][key]
  __shared__ char allow[Nn];
  int bid = blockIdx.x;
  int h = bid & 7, b = (bid >> 3) & 7, qt = bid >> 6;
  int tid = threadIdx.x, w = tid >> 6, lane = tid & 63, lr = lane & 15, lg = lane >> 4;
  int q0 = qt * 128 + w * 32;   // this wave's first q row

  ((int*)allow)[tid] = ((const int*)(allowC + b * Nn))[tid];
  __syncthreads();

  // Q fragments: 2 sub-tiles of 16 rows
  bf16x8 aq[2][2];
  #pragma unroll
  for (int qi = 0; qi < 2; qi++) {
    #pragma unroll
    for (int j = 0; j < 2; j++)
      aq[qi][j] = *(const bf16x8*)(Qbf + swz(b * Nn + q0 + qi * 16 + lr,
                                             h * 64 + j * 32 + lg * 8, Dd));
  }
  f32x4 acco[2][4] = {};
  float m_run[2][4], l_run[2][4];
  #pragma unroll
  for (int qi = 0; qi < 2; qi++)
  #pragma unroll
  for (int r = 0; r < 4; r++) { m_run[qi][r] = -1e30f; l_run[qi][r] = 0.0f; }
  const float scale = 0.044194173824159216f; // 1/sqrt(512)

  auto loadK = [&](bf16x8 (&kf)[4][2], int kb) {
    #pragma unroll
    for (int sub = 0; sub < 4; sub++)
    #pragma unroll
    for (int j = 0; j < 2; j++)
      kf[sub][j] = *(const bf16x8*)(Kbf + swz(b * Nn + kb + sub * 16 + lr,
                                              h * 64 + j * 32 + lg * 8, Dd));
  };

  auto process = [&](bf16x8 (&kf)[4][2], int kb, bf16x8 (&kfn)[4][2], int kbn) {
    loadK(kfn, kbn);                       // prefetch next K tile
    bf16x8 vb[2][4];                       // V^T frags for THIS tile, issued early
    #pragma unroll
    for (int ks = 0; ks < 2; ks++)
    #pragma unroll
    for (int t = 0; t < 4; t++)
      vb[ks][t] = *(const bf16x8*)(VT + swz(h * 64 + t * 16 + lr,
                                            b * Nn + kb + ks * 32 + lg * 8, Mrows));
    // S = Q K^T
    f32x4 accs[2][4] = {};
    #pragma unroll
    for (int sub = 0; sub < 4; sub++) {
      #pragma unroll
      for (int qi = 0; qi < 2; qi++) {
        accs[qi][sub] = mfma16(aq[qi][0], kf[sub][0], accs[qi][sub]);
        accs[qi][sub] = mfma16(aq[qi][1], kf[sub][1], accs[qi][sub]);
      }
    }
    #pragma unroll
    for (int qi = 0; qi < 2; qi++) {
      float sv[4][4];
      #pragma unroll
      for (int sub = 0; sub < 4; sub++) {
        int key = kb + sub * 16 + lr;
        int allowed = allow[key];
        #pragma unroll
        for (int r = 0; r < 4; r++) {
          int qrow = q0 + qi * 16 + lg * 4 + r;
          float s = accs[qi][sub][r] * scale;
          sv[sub][r] = (allowed || key == qrow) ? s : -1e30f;
        }
      }
      #pragma unroll
      for (int r = 0; r < 4; r++) {
        float m = fmaxf(fmaxf(sv[0][r], sv[1][r]), fmaxf(sv[2][r], sv[3][r]));
        #pragma unroll
        for (int off = 1; off < 16; off <<= 1) m = fmaxf(m, __shfl_xor(m, off));
        float mtot = fmaxf(m_run[qi][r], m);
        float alpha = __expf(m_run[qi][r] - mtot);
        float lsum = 0.0f;
        #pragma unroll
        for (int sub = 0; sub < 4; sub++) {
          sv[sub][r] = __expf(sv[sub][r] - mtot);
          lsum += sv[sub][r];
        }
        l_run[qi][r] = l_run[qi][r] * alpha + lsum;  // per-lane partial sum
        m_run[qi][r] = mtot;
        #pragma unroll
        for (int t = 0; t < 4; t++) acco[qi][t][r] *= alpha;
      }
      #pragma unroll
      for (int sub = 0; sub < 4; sub++)
      #pragma unroll
      for (int r = 0; r < 4; r++)
        Plds[w][qi * 16 + lg * 4 + r][sub * 16 + lr] = f2bf(sv[sub][r]);
    }
    // O += P @ V
    #pragma unroll
    for (int ks = 0; ks < 2; ks++) {
      bf16x8 pa0 = *(const bf16x8*)(&Plds[w][lr][ks * 32 + lg * 8]);
      bf16x8 pa1 = *(const bf16x8*)(&Plds[w][16 + lr][ks * 32 + lg * 8]);
      #pragma unroll
      for (int t = 0; t < 4; t++) {
        acco[0][t] = mfma16(pa0, vb[ks][t], acco[0][t]);
        acco[1][t] = mfma16(pa1, vb[ks][t], acco[1][t]);
      }
    }
  };

  bf16x8 kfA[4][2], kfB[4][2];
  loadK(kfA, 0);
  for (int kb = 0; kb < Nn; kb += 128) {
    int n1 = kb + 64;
    int n2 = (kb + 128 < Nn) ? (kb + 128) : 0;
    process(kfA, kb, kfB, n1);
    process(kfB, n1, kfA, n2);
  }

  // epilogue: reduce l across the 16-lane group, divide, write bf16 O (swz)
  #pragma unroll
  for (int qi = 0; qi < 2; qi++)
  #pragma unroll
  for (int r = 0; r < 4; r++) {
    float lsum = l_run[qi][r];
    #pragma unroll
    for (int off = 1; off < 16; off <<= 1) lsum += __shfl_xor(lsum, off);
    l_run[qi][r] = lsum;
  }
  #pragma unroll
  for (int qi = 0; qi < 2; qi++)
  #pragma unroll
  for (int t = 0; t < 4; t++)
  #pragma unroll
  for (int r = 0; r < 4; r++) {
    int q = b * Nn + q0 + qi * 16 + lg * 4 + r;
    Obf[swz(q, h * 64 + t * 16 + lr, Dd)] = f2bf(acco[qi][t][r] / l_run[qi][r]);
  }
}

// ---------------------------------------------------------------------------
extern "C" void kernel_launch(void* const* d_in, const int* in_sizes, int n_in,
                              void* d_out, int out_size, void* d_ws, size_t ws_size,
                              hipStream_t stream) {
  const float* X    = (const float*)d_in[0];
  const int*   train= (const int*)d_in[1];
  const int*   batch= (const int*)d_in[2];
  const float* Wq   = (const float*)d_in[3];
  const float* bq   = (const float*)d_in[4];
  const float* Wk   = (const float*)d_in[5];
  const float* bk   = (const float*)d_in[6];
  const float* Wv   = (const float*)d_in[7];
  const float* bv   = (const float*)d_in[8];
  const float* Wmix = (const float*)d_in[9];
  const float* bmix = (const float*)d_in[10];
  const float* ln0s = (const float*)d_in[11];
  const float* ln0b = (const float*)d_in[12];
  const float* ln1s = (const float*)d_in[13];
  const float* ln1b = (const float*)d_in[14];
  const float* wi0  = (const float*)d_in[15];
  const float* wi1  = (const float*)d_in[16];
  const float* wo   = (const float*)d_in[17];
  float* out = (float*)d_out;

  char* ws = (char*)d_ws;
  size_t off = 0;
  auto alloc = [&](size_t bytes) {
    off = (off + 255) & ~(size_t)255;
    void* p = ws + off; off += bytes; return p;
  };
  short* Xbf   = (short*)alloc((size_t)Mrows * Dd * 2);
  short* Xnbf  = (short*)alloc((size_t)Mrows * Dd * 2);
  short* Qbf   = (short*)alloc((size_t)Mrows * Dd * 2);
  short* Kbf   = (short*)alloc((size_t)Mrows * Dd * 2);
  short* VTg   = (short*)alloc((size_t)Dd * Mrows * 2);   // V^T swz [Dd][Mrows]
  short* Obf   = (short*)alloc((size_t)Mrows * Dd * 2);
  short* x1bf  = (short*)alloc((size_t)Mrows * Dd * 2);
  short* Gbf   = (short*)alloc((size_t)Mrows * FFd * 2);  // gelu(x1@wi0)
  short* FFbf  = (short*)alloc((size_t)Mrows * FFd * 2);
  short* WqT   = (short*)alloc((size_t)Dd * Dd * 2);
  short* WkT   = (short*)alloc((size_t)Dd * Dd * 2);
  short* WvT   = (short*)alloc((size_t)Dd * Dd * 2);
  short* WmixT = (short*)alloc((size_t)Dd * Dd * 2);
  short* wi0T  = (short*)alloc((size_t)FFd * Dd * 2);
  short* wi1T  = (short*)alloc((size_t)FFd * Dd * 2);
  short* woT   = (short*)alloc((size_t)Dd * FFd * 2);
  float* Qf    = (float*)alloc((size_t)Mrows * Dd * 4);
  float* Hcf   = (float*)alloc((size_t)Mrows * Dd * 4);
  char*  allowC= (char*)alloc((size_t)Mrows);

  dim3 blk(256);
  // weight transposes to bf16 swz[N][K] (batched)
  TJobs tj4; tj4.j[0] = {Wq, WqT}; tj4.j[1] = {Wk, WkT};
  tj4.j[2] = {Wv, WvT}; tj4.j[3] = {Wmix, WmixT};
  k_transpose_bf16<<<dim3(Dd / 32, Dd / 32, 4), blk, 0, stream>>>(tj4, Dd, Dd);
  TJobs tj2; tj2.j[0] = {wi0, wi0T}; tj2.j[1] = {wi1, wi1T};
  tj2.j[2] = {wi0, wi0T}; tj2.j[3] = {wi1, wi1T};
  k_transpose_bf16<<<dim3(FFd / 32, Dd / 32, 2), blk, 0, stream>>>(tj2, Dd, FFd);
  TJobs tj1; tj1.j[0] = {wo, woT}; tj1.j[1] = {wo, woT};
  tj1.j[2] = {wo, woT}; tj1.j[3] = {wo, woT};
  k_transpose_bf16<<<dim3(Dd / 32, FFd / 32, 1), blk, 0, stream>>>(tj1, FFd, Dd);

  // mask
  k_mask<<<Mrows / 256, blk, 0, stream>>>(train, batch, allowC);

  // LN0 (writes Xn bf16 and raw X bf16) -- one row per wave
  k_layernorm<true><<<Mrows / 4, blk, 0, stream>>>(X, ln0s, ln0b, Xnbf, Xbf);

  // Q (f32 for residual + bf16 for attention), K
  k_gemm128<64, 1, false, true,  true,  0><<<dim3(Dd / 64, Mrows / 128), blk, 0, stream>>>(
      Xnbf, WqT, bq, nullptr, nullptr, Qf, Qbf, Mrows, Dd, Dd);
  k_gemm128<64, 1, false, false, true,  0><<<dim3(Dd / 64, Mrows / 128), blk, 0, stream>>>(
      Xbf, WkT, bk, nullptr, nullptr, nullptr, Kbf, Mrows, Dd, Dd);
  // V^T = WvT @ Xbf^T  (bias indexed by output ROW = V column)
  k_gemm128<64, 2, false, false, true,  0><<<dim3(Mrows / 64, Dd / 128), blk, 0, stream>>>(
      WvT, Xbf, bv, nullptr, nullptr, nullptr, VTg, Dd, Mrows, Dd);

  // attention (barrier-free, 128 q-rows per block, XCD-pinned per head)
  k_attention<<<Bb * Hh * (Nn / 128), blk, 0, stream>>>(Qbf, Kbf, VTg, allowC, Obf);

  // Hc = O @ Wmix + bmix + Q
  k_gemm128<64, 1, true, true, false, 0><<<dim3(Dd / 64, Mrows / 128), blk, 0, stream>>>(
      Obf, WmixT, bmix, Qf, nullptr, Hcf, nullptr, Mrows, Dd, Dd);

  // LN1
  k_layernorm<false><<<Mrows / 4, blk, 0, stream>>>(Hcf, ln1s, ln1b, x1bf, nullptr);

  // FF part 1: G = gelu(x1 @ wi0)
  k_gemm128<128, 0, false, false, true, 1><<<dim3(FFd / 128, Mrows / 128), blk, 0, stream>>>(
      x1bf, wi0T, nullptr, nullptr, nullptr, nullptr, Gbf, Mrows, FFd, Dd);
  // FF part 2: FF = (x1 @ wi1) * G
  k_gemm128<128, 0, false, false, true, 2><<<dim3(FFd / 128, Mrows / 128), blk, 0, stream>>>(
      x1bf, wi1T, nullptr, nullptr, Gbf, nullptr, FFbf, Mrows, FFd, Dd);

  // out = Hc + FF @ wo
  k_gemm128<64, 0, true, true, false, 0><<<dim3(Dd / 64, Mrows / 128), blk, 0, stream>>>(
      FFbf, woT, nullptr, Hcf, nullptr, out, nullptr, Mrows, Dd, FFd);
}

// Round 12
// 228.109 us; speedup vs baseline: 1.1727x; 1.0809x over previous
//
#include <hip/hip_runtime.h>
#include <hip/hip_bf16.h>
#include <math.h>

#define DEV __device__ __forceinline__

using bf16x8 = __attribute__((ext_vector_type(8))) short;
using f32x4  = __attribute__((ext_vector_type(4))) float;

static constexpr int Bb = 8, Nn = 1024, Dd = 512, Hh = 8, DHd = 64, FFd = 2048;
static constexpr int Mrows = Bb * Nn; // 8192

DEV short f2bf(float f) {
  union { float f; unsigned u; } v; v.f = f;
  unsigned r = v.u + 0x7fffu + ((v.u >> 16) & 1u);
  return (short)(r >> 16);
}
DEV float bf2f(short s) {
  union { unsigned u; float f; } v; v.u = ((unsigned)(unsigned short)s) << 16;
  return v.f;
}

DEV f32x4 mfma16(bf16x8 a, bf16x8 b, f32x4 c) {
  return __builtin_amdgcn_mfma_f32_16x16x32_bf16(a, b, c, 0, 0, 0);
}

// swizzle64 layout for all bf16 operand buffers:
// element (row r, col k, leading-dim ld) lives at
//   (r>>6)*64*ld + (k>>3)*512 + (r&63)*8 + (k&7)
DEV size_t swz(int r, int k, int ld) {
  return (size_t)(r >> 6) * 64 * ld + (size_t)(k >> 3) * 512
       + (size_t)((r & 63) * 8 + (k & 7));
}

// async global->LDS, 16B per lane. LDS dest is wave-uniform base + lane*16.
DEV void gload16(const void* g, void* l) {
  __builtin_amdgcn_global_load_lds(
      (const __attribute__((address_space(1))) void*)g,
      (__attribute__((address_space(3))) void*)l, 16, 0, 0);
}

// gelu_new(g) = g * sigmoid(2 * 0.79788456 * (g + 0.044715 g^3))
DEV float gelu_fast(float g) {
  float u2 = 1.5957691216057308f * (g + 0.044715f * g * g * g);
  return g / (1.0f + __expf(-u2));
}

// 2-D per-XCD chunk swizzle.
DEV void xcd_tile(int gx, int gy, int& trow, int& tcol) {
  int wg = blockIdx.y * gx + blockIdx.x;
  int xcd = wg & 7, idx = wg >> 3;
  int XC = (gx >= 16) ? 2 : 1, XR = 8 / XC;
  int lcx = gx / XC, lcy = gy / XR;
  trow = (xcd / XC) * lcy + idx / lcx;
  tcol = (xcd % XC) * lcx + idx % lcx;
}

// ---------------- batched transpose f32 [K][N] -> bf16 swz[N][K] ------------
struct TJob { const float* src; short* dst; };
struct TJobs { TJob j[4]; };
__global__ __launch_bounds__(256)
void k_transpose_bf16(TJobs jobs, int K, int N) {
  const float* W = jobs.j[blockIdx.z].src;
  short* WT = jobs.j[blockIdx.z].dst;
  __shared__ float tile[32][33];
  int nb = blockIdx.x * 32, kb = blockIdx.y * 32;
  int tx = threadIdx.x & 31, ty = threadIdx.x >> 5;
  #pragma unroll
  for (int i = ty; i < 32; i += 8)
    tile[i][tx] = W[(size_t)(kb + i) * N + nb + tx];
  __syncthreads();
  #pragma unroll
  for (int i = ty; i < 32; i += 8)
    WT[swz(nb + i, kb + tx, K)] = f2bf(tile[tx][i]);
}

// ---------------- mask precompute: allowC[b][n] = (train|batch)!=0 ----------
__global__ __launch_bounds__(256)
void k_mask(const int* __restrict__ train, const int* __restrict__ batch,
            char* __restrict__ allowC) {
  int i = blockIdx.x * 256 + threadIdx.x;
  allowC[i] = ((train[i] | batch[i]) != 0) ? 1 : 0;
}

// ---------------- layernorm: one row per WAVE, no barriers ------------------
template<bool WRITE_RAW>
__global__ __launch_bounds__(256)
void k_layernorm(const float* __restrict__ X, const float* __restrict__ sc,
                 const float* __restrict__ bi, short* __restrict__ out,
                 short* __restrict__ raw) {
  int w = threadIdx.x >> 6, lane = threadIdx.x & 63;
  int row = blockIdx.x * 4 + w;
  const float* x = X + (size_t)row * Dd + lane * 8;
  f32x4 a = *(const f32x4*)x;
  f32x4 b = *(const f32x4*)(x + 4);
  float p = a[0] + a[1] + a[2] + a[3] + b[0] + b[1] + b[2] + b[3];
  #pragma unroll
  for (int off = 1; off < 64; off <<= 1) p += __shfl_xor(p, off);
  float mean = p * (1.0f / Dd);
  float d[8];
  #pragma unroll
  for (int j = 0; j < 4; j++) { d[j] = a[j] - mean; d[4 + j] = b[j] - mean; }
  float q = 0.0f;
  #pragma unroll
  for (int j = 0; j < 8; j++) q += d[j] * d[j];
  #pragma unroll
  for (int off = 1; off < 64; off <<= 1) q += __shfl_xor(q, off);
  float rs = rsqrtf(q * (1.0f / Dd) + 1e-12f);
  int c0 = lane * 8;
  f32x4 s0 = *(const f32x4*)(sc + c0), s1 = *(const f32x4*)(sc + c0 + 4);
  f32x4 b0 = *(const f32x4*)(bi + c0), b1 = *(const f32x4*)(bi + c0 + 4);
  bf16x8 o;
  #pragma unroll
  for (int j = 0; j < 4; j++) {
    o[j]     = f2bf(d[j] * rs * s0[j] + b0[j]);
    o[4 + j] = f2bf(d[4 + j] * rs * s1[j] + b1[j]);
  }
  *(bf16x8*)(out + swz(row, c0, Dd)) = o;
  if (WRITE_RAW) {
    bf16x8 rv;
    #pragma unroll
    for (int j = 0; j < 4; j++) { rv[j] = f2bf(a[j]); rv[4 + j] = f2bf(b[j]); }
    *(bf16x8*)(raw + swz(row, c0, Dd)) = rv;
  }
}

// ---------------- LDS-staged bf16 MFMA GEMM: C = A[M][K] @ BT[N][K]^T -------
// A/BT in swz layout. 128 x BN tile, BK=32, 4 waves, 2-buf stage-ahead.
// BIASM: 0 none, 1 bias[col], 2 bias[row].  EPI: 0 none, 1 gelu, 2 mul-by-G.
template<int BN, int BIASM, bool RES, bool WF, bool WB, int EPI>
__global__ __launch_bounds__(256, 4)
void k_gemm128(const short* __restrict__ A, const short* __restrict__ BT,
               const float* __restrict__ bias, const float* __restrict__ res,
               const short* __restrict__ gpre,
               float* __restrict__ outF, short* __restrict__ outB,
               int M, int N, int K) {
  constexpr int FN = BN / 32;   // frag cols per wave
  __shared__ short lA[2][128 * 32];
  __shared__ short lB[2][BN * 32];
  int tid = threadIdx.x, w = tid >> 6, lane = tid & 63;
  int lr = lane & 15, lg = lane >> 4;
  int wr = w >> 1, wc = w & 1;
  int trow, tcol;
  xcd_tile(gridDim.x, gridDim.y, trow, tcol);
  int row0 = trow * 128, col0 = tcol * BN;
  f32x4 acc[4][FN] = {};

  auto stage = [&](int buf, int k0) {
    #pragma unroll
    for (int i = 0; i < 2; i++) {            // A: 8 chunks of 1KB
      int c = i * 4 + w;
      gload16(A + swz(row0 + (c & 1) * 64 + lane, k0 + (c >> 1) * 8, K),
              &lA[buf][c * 512]);
    }
    #pragma unroll
    for (int i = 0; i < BN / 64; i++) {      // B: BN/16 chunks
      int c = i * 4 + w;
      if (BN == 128)
        gload16(BT + swz(col0 + (c & 1) * 64 + lane, k0 + (c >> 1) * 8, K),
                &lB[buf][c * 512]);
      else
        gload16(BT + swz(col0 + lane, k0 + c * 8, K), &lB[buf][c * 512]);
    }
  };

  stage(0, 0);
  __syncthreads();
  int nt = K / 32, buf = 0;
  for (int t = 0; t < nt; t++) {
    if (t + 1 < nt) stage(buf ^ 1, (t + 1) * 32);
    bf16x8 af[4];
    #pragma unroll
    for (int m = 0; m < 4; m++)
      af[m] = *(const bf16x8*)&lA[buf][lg * 1024 + (wr * 64 + m * 16 + lr) * 8];
    #pragma unroll
    for (int n = 0; n < FN; n++) {
      bf16x8 bfr = *(const bf16x8*)&lB[buf][lg * (BN * 8) + (wc * (BN / 2) + n * 16 + lr) * 8];
      #pragma unroll
      for (int m = 0; m < 4; m++)
        acc[m][n] = mfma16(af[m], bfr, acc[m][n]);
    }
    __syncthreads();
    buf ^= 1;
  }

  #pragma unroll
  for (int n = 0; n < FN; n++) {
    int col = col0 + wc * (BN / 2) + n * 16 + lr;
    float bv = (BIASM == 1) ? bias[col] : 0.0f;
    #pragma unroll
    for (int m = 0; m < 4; m++) {
      #pragma unroll
      for (int r = 0; r < 4; r++) {
        int rowg = row0 + wr * 64 + m * 16 + lg * 4 + r;
        float vv = acc[m][n][r] + bv;
        if (BIASM == 2) vv += bias[rowg];
        if (RES) vv += res[(size_t)rowg * N + col];
        if (EPI == 1) vv = gelu_fast(vv);
        if (EPI == 2) vv *= bf2f(gpre[swz(rowg, col, N)]);
        if (WF) outF[(size_t)rowg * N + col] = vv;
        if (WB) outB[swz(rowg, col, N)] = f2bf(vv);
      }
    }
  }
}

// ---------------- flash attention, barrier-free, pipelined ------------------
// Qbf/Kbf swz over [Mrows][Dd]; VT swz over [Dd][Mrows].
// Softmax: additive LDS mask + defer-max (THR=8, m_run init 0).
__global__ __launch_bounds__(256, 2)
void k_attention(const short* __restrict__ Qbf, const short* __restrict__ Kbf,
                 const short* __restrict__ VT, const char* __restrict__ allowC,
                 short* __restrict__ Obf) {
  __shared__ __align__(16) short Plds[4][32][72];  // per-wave P: [q][key]
  __shared__ float maskF[Nn];                      // 0 or -1e30 per key
  int bid = blockIdx.x;
  int h = bid & 7, b = (bid >> 3) & 7, qt = bid >> 6;
  int tid = threadIdx.x, w = tid >> 6, lane = tid & 63, lr = lane & 15, lg = lane >> 4;
  int q0 = qt * 128 + w * 32;   // this wave's first q row

  {
    const char* ac = allowC + b * Nn;
    #pragma unroll
    for (int j = 0; j < 4; j++) {
      int i = tid * 4 + j;
      maskF[i] = ac[i] ? 0.0f : -1e30f;
    }
  }
  __syncthreads();

  // Q fragments: 2 sub-tiles of 16 rows
  bf16x8 aq[2][2];
  #pragma unroll
  for (int qi = 0; qi < 2; qi++) {
    #pragma unroll
    for (int j = 0; j < 2; j++)
      aq[qi][j] = *(const bf16x8*)(Qbf + swz(b * Nn + q0 + qi * 16 + lr,
                                             h * 64 + j * 32 + lg * 8, Dd));
  }
  f32x4 acco[2][4] = {};
  float m_run[2][4], l_run[2][4];
  #pragma unroll
  for (int qi = 0; qi < 2; qi++)
  #pragma unroll
  for (int r = 0; r < 4; r++) { m_run[qi][r] = 0.0f; l_run[qi][r] = 0.0f; }
  const float scale = 0.044194173824159216f; // 1/sqrt(512)

  auto loadK = [&](bf16x8 (&kf)[4][2], int kb) {
    #pragma unroll
    for (int sub = 0; sub < 4; sub++)
    #pragma unroll
    for (int j = 0; j < 2; j++)
      kf[sub][j] = *(const bf16x8*)(Kbf + swz(b * Nn + kb + sub * 16 + lr,
                                              h * 64 + j * 32 + lg * 8, Dd));
  };

  auto process = [&](bf16x8 (&kf)[4][2], int kb, bf16x8 (&kfn)[4][2], int kbn) {
    loadK(kfn, kbn);                       // prefetch next K tile
    bf16x8 vb[2][4];                       // V^T frags for THIS tile, issued early
    #pragma unroll
    for (int ks = 0; ks < 2; ks++)
    #pragma unroll
    for (int t = 0; t < 4; t++)
      vb[ks][t] = *(const bf16x8*)(VT + swz(h * 64 + t * 16 + lr,
                                            b * Nn + kb + ks * 32 + lg * 8, Mrows));
    // S = Q K^T
    f32x4 accs[2][4] = {};
    #pragma unroll
    for (int sub = 0; sub < 4; sub++) {
      #pragma unroll
      for (int qi = 0; qi < 2; qi++) {
        accs[qi][sub] = mfma16(aq[qi][0], kf[sub][0], accs[qi][sub]);
        accs[qi][sub] = mfma16(aq[qi][1], kf[sub][1], accs[qi][sub]);
      }
    }
    // additive mask
    float mk[4];
    #pragma unroll
    for (int sub = 0; sub < 4; sub++) mk[sub] = maskF[kb + sub * 16 + lr];
    float sv[2][4][4];
    #pragma unroll
    for (int qi = 0; qi < 2; qi++)
    #pragma unroll
    for (int sub = 0; sub < 4; sub++)
    #pragma unroll
    for (int r = 0; r < 4; r++)
      sv[qi][sub][r] = accs[qi][sub][r] * scale + mk[sub];
    // diagonal always attendable -- only in the tile containing this wave's rows
    if (kb == (q0 & ~63)) {
      #pragma unroll
      for (int qi = 0; qi < 2; qi++)
      #pragma unroll
      for (int sub = 0; sub < 4; sub++) {
        int key = kb + sub * 16 + lr;
        #pragma unroll
        for (int r = 0; r < 4; r++) {
          int qrow = q0 + qi * 16 + lg * 4 + r;
          if (key == qrow) sv[qi][sub][r] = accs[qi][sub][r] * scale;
        }
      }
    }
    // defer-max: skip rescale unless some row max exceeds m_run + 8
    bool allok = true;
    float pmax[2][4];
    #pragma unroll
    for (int qi = 0; qi < 2; qi++)
    #pragma unroll
    for (int r = 0; r < 4; r++) {
      pmax[qi][r] = fmaxf(fmaxf(sv[qi][0][r], sv[qi][1][r]),
                          fmaxf(sv[qi][2][r], sv[qi][3][r]));
      allok = allok && (pmax[qi][r] <= m_run[qi][r] + 8.0f);
    }
    if (!__all(allok)) {
      #pragma unroll
      for (int qi = 0; qi < 2; qi++)
      #pragma unroll
      for (int r = 0; r < 4; r++) {
        float m = pmax[qi][r];
        #pragma unroll
        for (int off = 1; off < 16; off <<= 1) m = fmaxf(m, __shfl_xor(m, off));
        float mtot = fmaxf(m_run[qi][r], m);
        float alpha = __expf(m_run[qi][r] - mtot);
        l_run[qi][r] *= alpha;
        m_run[qi][r] = mtot;
        #pragma unroll
        for (int t = 0; t < 4; t++) acco[qi][t][r] *= alpha;
      }
    }
    // exps + P write (per-lane partial l sums; reduced in epilogue)
    #pragma unroll
    for (int qi = 0; qi < 2; qi++) {
      #pragma unroll
      for (int sub = 0; sub < 4; sub++)
      #pragma unroll
      for (int r = 0; r < 4; r++) {
        float e = __expf(sv[qi][sub][r] - m_run[qi][r]);
        l_run[qi][r] += e;
        Plds[w][qi * 16 + lg * 4 + r][sub * 16 + lr] = f2bf(e);
      }
    }
    // O += P @ V
    #pragma unroll
    for (int ks = 0; ks < 2; ks++) {
      bf16x8 pa0 = *(const bf16x8*)(&Plds[w][lr][ks * 32 + lg * 8]);
      bf16x8 pa1 = *(const bf16x8*)(&Plds[w][16 + lr][ks * 32 + lg * 8]);
      #pragma unroll
      for (int t = 0; t < 4; t++) {
        acco[0][t] = mfma16(pa0, vb[ks][t], acco[0][t]);
        acco[1][t] = mfma16(pa1, vb[ks][t], acco[1][t]);
      }
    }
  };

  bf16x8 kfA[4][2], kfB[4][2];
  loadK(kfA, 0);
  for (int kb = 0; kb < Nn; kb += 128) {
    int n1 = kb + 64;
    int n2 = (kb + 128 < Nn) ? (kb + 128) : 0;
    process(kfA, kb, kfB, n1);
    process(kfB, n1, kfA, n2);
  }

  // epilogue: reduce l across the 16-lane group, divide, write bf16 O (swz)
  #pragma unroll
  for (int qi = 0; qi < 2; qi++)
  #pragma unroll
  for (int r = 0; r < 4; r++) {
    float lsum = l_run[qi][r];
    #pragma unroll
    for (int off = 1; off < 16; off <<= 1) lsum += __shfl_xor(lsum, off);
    l_run[qi][r] = lsum;
  }
  #pragma unroll
  for (int qi = 0; qi < 2; qi++)
  #pragma unroll
  for (int t = 0; t < 4; t++)
  #pragma unroll
  for (int r = 0; r < 4; r++) {
    int q = b * Nn + q0 + qi * 16 + lg * 4 + r;
    Obf[swz(q, h * 64 + t * 16 + lr, Dd)] = f2bf(acco[qi][t][r] / l_run[qi][r]);
  }
}

// ---------------------------------------------------------------------------
extern "C" void kernel_launch(void* const* d_in, const int* in_sizes, int n_in,
                              void* d_out, int out_size, void* d_ws, size_t ws_size,
                              hipStream_t stream) {
  const float* X    = (const float*)d_in[0];
  const int*   train= (const int*)d_in[1];
  const int*   batch= (const int*)d_in[2];
  const float* Wq   = (const float*)d_in[3];
  const float* bq   = (const float*)d_in[4];
  const float* Wk   = (const float*)d_in[5];
  const float* bk   = (const float*)d_in[6];
  const float* Wv   = (const float*)d_in[7];
  const float* bv   = (const float*)d_in[8];
  const float* Wmix = (const float*)d_in[9];
  const float* bmix = (const float*)d_in[10];
  const float* ln0s = (const float*)d_in[11];
  const float* ln0b = (const float*)d_in[12];
  const float* ln1s = (const float*)d_in[13];
  const float* ln1b = (const float*)d_in[14];
  const float* wi0  = (const float*)d_in[15];
  const float* wi1  = (const float*)d_in[16];
  const float* wo   = (const float*)d_in[17];
  float* out = (float*)d_out;

  char* ws = (char*)d_ws;
  size_t off = 0;
  auto alloc = [&](size_t bytes) {
    off = (off + 255) & ~(size_t)255;
    void* p = ws + off; off += bytes; return p;
  };
  short* Xbf   = (short*)alloc((size_t)Mrows * Dd * 2);
  short* Xnbf  = (short*)alloc((size_t)Mrows * Dd * 2);
  short* Qbf   = (short*)alloc((size_t)Mrows * Dd * 2);
  short* Kbf   = (short*)alloc((size_t)Mrows * Dd * 2);
  short* VTg   = (short*)alloc((size_t)Dd * Mrows * 2);   // V^T swz [Dd][Mrows]
  short* Obf   = (short*)alloc((size_t)Mrows * Dd * 2);
  short* x1bf  = (short*)alloc((size_t)Mrows * Dd * 2);
  short* Gbf   = (short*)alloc((size_t)Mrows * FFd * 2);  // gelu(x1@wi0)
  short* FFbf  = (short*)alloc((size_t)Mrows * FFd * 2);
  short* WqT   = (short*)alloc((size_t)Dd * Dd * 2);
  short* WkT   = (short*)alloc((size_t)Dd * Dd * 2);
  short* WvT   = (short*)alloc((size_t)Dd * Dd * 2);
  short* WmixT = (short*)alloc((size_t)Dd * Dd * 2);
  short* wi0T  = (short*)alloc((size_t)FFd * Dd * 2);
  short* wi1T  = (short*)alloc((size_t)FFd * Dd * 2);
  short* woT   = (short*)alloc((size_t)Dd * FFd * 2);
  float* Qf    = (float*)alloc((size_t)Mrows * Dd * 4);
  float* Hcf   = (float*)alloc((size_t)Mrows * Dd * 4);
  char*  allowC= (char*)alloc((size_t)Mrows);

  dim3 blk(256);
  // weight transposes to bf16 swz[N][K] (batched)
  TJobs tj4; tj4.j[0] = {Wq, WqT}; tj4.j[1] = {Wk, WkT};
  tj4.j[2] = {Wv, WvT}; tj4.j[3] = {Wmix, WmixT};
  k_transpose_bf16<<<dim3(Dd / 32, Dd / 32, 4), blk, 0, stream>>>(tj4, Dd, Dd);
  TJobs tj2; tj2.j[0] = {wi0, wi0T}; tj2.j[1] = {wi1, wi1T};
  tj2.j[2] = {wi0, wi0T}; tj2.j[3] = {wi1, wi1T};
  k_transpose_bf16<<<dim3(FFd / 32, Dd / 32, 2), blk, 0, stream>>>(tj2, Dd, FFd);
  TJobs tj1; tj1.j[0] = {wo, woT}; tj1.j[1] = {wo, woT};
  tj1.j[2] = {wo, woT}; tj1.j[3] = {wo, woT};
  k_transpose_bf16<<<dim3(Dd / 32, FFd / 32, 1), blk, 0, stream>>>(tj1, FFd, Dd);

  // mask
  k_mask<<<Mrows / 256, blk, 0, stream>>>(train, batch, allowC);

  // LN0 (writes Xn bf16 and raw X bf16) -- one row per wave
  k_layernorm<true><<<Mrows / 4, blk, 0, stream>>>(X, ln0s, ln0b, Xnbf, Xbf);

  // Q (f32 for residual + bf16 for attention), K
  k_gemm128<64, 1, false, true,  true,  0><<<dim3(Dd / 64, Mrows / 128), blk, 0, stream>>>(
      Xnbf, WqT, bq, nullptr, nullptr, Qf, Qbf, Mrows, Dd, Dd);
  k_gemm128<64, 1, false, false, true,  0><<<dim3(Dd / 64, Mrows / 128), blk, 0, stream>>>(
      Xbf, WkT, bk, nullptr, nullptr, nullptr, Kbf, Mrows, Dd, Dd);
  // V^T = WvT @ Xbf^T  (bias indexed by output ROW = V column)
  k_gemm128<64, 2, false, false, true,  0><<<dim3(Mrows / 64, Dd / 128), blk, 0, stream>>>(
      WvT, Xbf, bv, nullptr, nullptr, nullptr, VTg, Dd, Mrows, Dd);

  // attention (barrier-free, 128 q-rows per block, XCD-pinned per head)
  k_attention<<<Bb * Hh * (Nn / 128), blk, 0, stream>>>(Qbf, Kbf, VTg, allowC, Obf);

  // Hc = O @ Wmix + bmix + Q
  k_gemm128<64, 1, true, true, false, 0><<<dim3(Dd / 64, Mrows / 128), blk, 0, stream>>>(
      Obf, WmixT, bmix, Qf, nullptr, Hcf, nullptr, Mrows, Dd, Dd);

  // LN1
  k_layernorm<false><<<Mrows / 4, blk, 0, stream>>>(Hcf, ln1s, ln1b, x1bf, nullptr);

  // FF part 1: G = gelu(x1 @ wi0)
  k_gemm128<128, 0, false, false, true, 1><<<dim3(FFd / 128, Mrows / 128), blk, 0, stream>>>(
      x1bf, wi0T, nullptr, nullptr, nullptr, nullptr, Gbf, Mrows, FFd, Dd);
  // FF part 2: FF = (x1 @ wi1) * G
  k_gemm128<128, 0, false, false, true, 2><<<dim3(FFd / 128, Mrows / 128), blk, 0, stream>>>(
      x1bf, wi1T, nullptr, nullptr, Gbf, nullptr, FFbf, Mrows, FFd, Dd);

  // out = Hc + FF @ wo
  k_gemm128<64, 0, true, true, false, 0><<<dim3(Dd / 64, Mrows / 128), blk, 0, stream>>>(
      FFbf, woT, nullptr, Hcf, nullptr, out, nullptr, Mrows, Dd, FFd);
}

// Round 14
// 207.461 us; speedup vs baseline: 1.2894x; 1.0995x over previous
//
#include <hip/hip_runtime.h>
#include <hip/hip_bf16.h>
#include <math.h>

#define DEV __device__ __forceinline__

using bf16x8 = __attribute__((ext_vector_type(8))) short;
using f32x4  = __attribute__((ext_vector_type(4))) float;

static constexpr int Bb = 8, Nn = 1024, Dd = 512, Hh = 8, DHd = 64, FFd = 2048;
static constexpr int Mrows = Bb * Nn; // 8192

DEV short f2bf(float f) {
  union { float f; unsigned u; } v; v.f = f;
  unsigned r = v.u + 0x7fffu + ((v.u >> 16) & 1u);
  return (short)(r >> 16);
}
DEV float bf2f(short s) {
  union { unsigned u; float f; } v; v.u = ((unsigned)(unsigned short)s) << 16;
  return v.f;
}

DEV f32x4 mfma16(bf16x8 a, bf16x8 b, f32x4 c) {
  return __builtin_amdgcn_mfma_f32_16x16x32_bf16(a, b, c, 0, 0, 0);
}

// swizzle64 layout for all bf16 operand buffers:
// element (row r, col k, leading-dim ld) lives at
//   (r>>6)*64*ld + (k>>3)*512 + (r&63)*8 + (k&7)
DEV size_t swz(int r, int k, int ld) {
  return (size_t)(r >> 6) * 64 * ld + (size_t)(k >> 3) * 512
       + (size_t)((r & 63) * 8 + (k & 7));
}

// async global->LDS, 16B per lane. LDS dest is wave-uniform base + lane*16.
DEV void gload16(const void* g, void* l) {
  __builtin_amdgcn_global_load_lds(
      (const __attribute__((address_space(1))) void*)g,
      (__attribute__((address_space(3))) void*)l, 16, 0, 0);
}

// gelu_new(g) = g * sigmoid(2 * 0.79788456 * (g + 0.044715 g^3))
DEV float gelu_fast(float g) {
  float u2 = 1.5957691216057308f * (g + 0.044715f * g * g * g);
  return g / (1.0f + __expf(-u2));
}

// 2-D per-XCD chunk swizzle.
DEV void xcd_tile(int gx, int gy, int& trow, int& tcol) {
  int wg = blockIdx.y * gx + blockIdx.x;
  int xcd = wg & 7, idx = wg >> 3;
  int XC = (gx >= 16) ? 2 : 1, XR = 8 / XC;
  int lcx = gx / XC, lcy = gy / XR;
  trow = (xcd / XC) * lcy + idx / lcx;
  tcol = (xcd % XC) * lcx + idx % lcx;
}

// ---------------- batched transpose f32 [K][N] -> bf16 swz[N][K] ------------
struct TJob { const float* src; short* dst; };
struct TJobs { TJob j[4]; };
__global__ __launch_bounds__(256)
void k_transpose_bf16(TJobs jobs, int K, int N) {
  const float* W = jobs.j[blockIdx.z].src;
  short* WT = jobs.j[blockIdx.z].dst;
  __shared__ float tile[32][33];
  int nb = blockIdx.x * 32, kb = blockIdx.y * 32;
  int tx = threadIdx.x & 31, ty = threadIdx.x >> 5;
  #pragma unroll
  for (int i = ty; i < 32; i += 8)
    tile[i][tx] = W[(size_t)(kb + i) * N + nb + tx];
  __syncthreads();
  #pragma unroll
  for (int i = ty; i < 32; i += 8)
    WT[swz(nb + i, kb + tx, K)] = f2bf(tile[tx][i]);
}

// ---------------- mask precompute: allowC[b][n] = (train|batch)!=0 ----------
__global__ __launch_bounds__(256)
void k_mask(const int* __restrict__ train, const int* __restrict__ batch,
            char* __restrict__ allowC) {
  int i = blockIdx.x * 256 + threadIdx.x;
  allowC[i] = ((train[i] | batch[i]) != 0) ? 1 : 0;
}

// ---------------- layernorm: one row per WAVE, no barriers ------------------
template<bool WRITE_RAW>
__global__ __launch_bounds__(256)
void k_layernorm(const float* __restrict__ X, const float* __restrict__ sc,
                 const float* __restrict__ bi, short* __restrict__ out,
                 short* __restrict__ raw) {
  int w = threadIdx.x >> 6, lane = threadIdx.x & 63;
  int row = blockIdx.x * 4 + w;
  const float* x = X + (size_t)row * Dd + lane * 8;
  f32x4 a = *(const f32x4*)x;
  f32x4 b = *(const f32x4*)(x + 4);
  float p = a[0] + a[1] + a[2] + a[3] + b[0] + b[1] + b[2] + b[3];
  #pragma unroll
  for (int off = 1; off < 64; off <<= 1) p += __shfl_xor(p, off);
  float mean = p * (1.0f / Dd);
  float d[8];
  #pragma unroll
  for (int j = 0; j < 4; j++) { d[j] = a[j] - mean; d[4 + j] = b[j] - mean; }
  float q = 0.0f;
  #pragma unroll
  for (int j = 0; j < 8; j++) q += d[j] * d[j];
  #pragma unroll
  for (int off = 1; off < 64; off <<= 1) q += __shfl_xor(q, off);
  float rs = rsqrtf(q * (1.0f / Dd) + 1e-12f);
  int c0 = lane * 8;
  f32x4 s0 = *(const f32x4*)(sc + c0), s1 = *(const f32x4*)(sc + c0 + 4);
  f32x4 b0 = *(const f32x4*)(bi + c0), b1 = *(const f32x4*)(bi + c0 + 4);
  bf16x8 o;
  #pragma unroll
  for (int j = 0; j < 4; j++) {
    o[j]     = f2bf(d[j] * rs * s0[j] + b0[j]);
    o[4 + j] = f2bf(d[4 + j] * rs * s1[j] + b1[j]);
  }
  *(bf16x8*)(out + swz(row, c0, Dd)) = o;
  if (WRITE_RAW) {
    bf16x8 rv;
    #pragma unroll
    for (int j = 0; j < 4; j++) { rv[j] = f2bf(a[j]); rv[4 + j] = f2bf(b[j]); }
    *(bf16x8*)(raw + swz(row, c0, Dd)) = rv;
  }
}

// ---------------- LDS-staged bf16 MFMA GEMM: C = A[M][K] @ BT[N][K]^T -------
// A/BT in swz layout. 128 x BN tile, BK k-depth, 4 waves, 2-buf stage-ahead.
// Plane-major LDS [k-octet][row][8]: conflict-free reads, coalesced staging.
// BIASM: 0 none, 1 bias[col], 2 bias[row].
// RESM:  0 none, 1 f32 row-major, 2 bf16 swz.
// EPI:   0 none, 1 gelu, 2 mul-by-G.
template<int BN, int BK, int BIASM, int RESM, bool WF, bool WB, int EPI>
__global__ __launch_bounds__(256, 4)
void k_gemm128(const short* __restrict__ A, const short* __restrict__ BT,
               const float* __restrict__ bias, const float* __restrict__ resF,
               const short* __restrict__ resB, const short* __restrict__ gpre,
               float* __restrict__ outF, short* __restrict__ outB,
               int M, int N, int K) {
  constexpr int FN = BN / 32;   // frag cols per wave
  __shared__ short lA[2][128 * BK];
  __shared__ short lB[2][BN * BK];
  int tid = threadIdx.x, w = tid >> 6, lane = tid & 63;
  int lr = lane & 15, lg = lane >> 4;
  int wr = w >> 1, wc = w & 1;
  int trow, tcol;
  xcd_tile(gridDim.x, gridDim.y, trow, tcol);
  int row0 = trow * 128, col0 = tcol * BN;
  f32x4 acc[4][FN] = {};

  auto stage = [&](int buf, int k0) {
    // A: 128 x BK = BK/4 KB -> BK/16 iters of 4 chunks; chunk c: octet c>>1, half c&1
    #pragma unroll
    for (int i = 0; i < BK / 16; i++) {
      int c = i * 4 + w;
      gload16(A + swz(row0 + (c & 1) * 64 + lane, k0 + (c >> 1) * 8, K),
              &lA[buf][c * 512]);
    }
    // B: BN x BK -> BN*BK/512 chunks
    #pragma unroll
    for (int i = 0; i < (BN * BK) / 2048; i++) {
      int c = i * 4 + w;
      if (BN == 128)
        gload16(BT + swz(col0 + (c & 1) * 64 + lane, k0 + (c >> 1) * 8, K),
                &lB[buf][c * 512]);
      else
        gload16(BT + swz(col0 + lane, k0 + c * 8, K), &lB[buf][c * 512]);
    }
  };

  stage(0, 0);
  __syncthreads();
  int nt = K / BK, buf = 0;
  for (int t = 0; t < nt; t++) {
    if (t + 1 < nt) stage(buf ^ 1, (t + 1) * BK);
    #pragma unroll
    for (int kk = 0; kk < BK / 32; kk++) {
      bf16x8 af[4];
      #pragma unroll
      for (int m = 0; m < 4; m++)
        af[m] = *(const bf16x8*)&lA[buf][(kk * 4 + lg) * 1024 + (wr * 64 + m * 16 + lr) * 8];
      #pragma unroll
      for (int n = 0; n < FN; n++) {
        bf16x8 bfr = *(const bf16x8*)&lB[buf][(kk * 4 + lg) * (BN * 8)
                                              + (wc * (BN / 2) + n * 16 + lr) * 8];
        #pragma unroll
        for (int m = 0; m < 4; m++)
          acc[m][n] = mfma16(af[m], bfr, acc[m][n]);
      }
    }
    __syncthreads();
    buf ^= 1;
  }

  #pragma unroll
  for (int n = 0; n < FN; n++) {
    int col = col0 + wc * (BN / 2) + n * 16 + lr;
    float bv = (BIASM == 1) ? bias[col] : 0.0f;
    #pragma unroll
    for (int m = 0; m < 4; m++) {
      #pragma unroll
      for (int r = 0; r < 4; r++) {
        int rowg = row0 + wr * 64 + m * 16 + lg * 4 + r;
        float vv = acc[m][n][r] + bv;
        if (BIASM == 2) vv += bias[rowg];
        if (RESM == 1) vv += resF[(size_t)rowg * N + col];
        if (RESM == 2) vv += bf2f(resB[swz(rowg, col, N)]);
        if (EPI == 1) vv = gelu_fast(vv);
        if (EPI == 2) vv *= bf2f(gpre[swz(rowg, col, N)]);
        if (WF) outF[(size_t)rowg * N + col] = vv;
        if (WB) outB[swz(rowg, col, N)] = f2bf(vv);
      }
    }
  }
}

// ---------------- flash attention, barrier-free, pipelined ------------------
// Qbf/Kbf swz over [Mrows][Dd]; VT swz over [Dd][Mrows].
// Softmax: additive LDS mask + defer-max (THR=8, m_run init 0).
__global__ __launch_bounds__(256, 2)
void k_attention(const short* __restrict__ Qbf, const short* __restrict__ Kbf,
                 const short* __restrict__ VT, const char* __restrict__ allowC,
                 short* __restrict__ Obf) {
  __shared__ __align__(16) short Plds[4][32][72];  // per-wave P: [q][key]
  __shared__ float maskF[Nn];                      // 0 or -1e30 per key
  int bid = blockIdx.x;
  int h = bid & 7, b = (bid >> 3) & 7, qt = bid >> 6;
  int tid = threadIdx.x, w = tid >> 6, lane = tid & 63, lr = lane & 15, lg = lane >> 4;
  int q0 = qt * 128 + w * 32;   // this wave's first q row

  {
    const char* ac = allowC + b * Nn;
    #pragma unroll
    for (int j = 0; j < 4; j++) {
      int i = tid * 4 + j;
      maskF[i] = ac[i] ? 0.0f : -1e30f;
    }
  }
  __syncthreads();

  // Q fragments: 2 sub-tiles of 16 rows
  bf16x8 aq[2][2];
  #pragma unroll
  for (int qi = 0; qi < 2; qi++) {
    #pragma unroll
    for (int j = 0; j < 2; j++)
      aq[qi][j] = *(const bf16x8*)(Qbf + swz(b * Nn + q0 + qi * 16 + lr,
                                             h * 64 + j * 32 + lg * 8, Dd));
  }
  f32x4 acco[2][4] = {};
  float m_run[2][4], l_run[2][4];
  #pragma unroll
  for (int qi = 0; qi < 2; qi++)
  #pragma unroll
  for (int r = 0; r < 4; r++) { m_run[qi][r] = 0.0f; l_run[qi][r] = 0.0f; }
  const float scale = 0.044194173824159216f; // 1/sqrt(512)

  auto loadK = [&](bf16x8 (&kf)[4][2], int kb) {
    #pragma unroll
    for (int sub = 0; sub < 4; sub++)
    #pragma unroll
    for (int j = 0; j < 2; j++)
      kf[sub][j] = *(const bf16x8*)(Kbf + swz(b * Nn + kb + sub * 16 + lr,
                                              h * 64 + j * 32 + lg * 8, Dd));
  };

  auto process = [&](bf16x8 (&kf)[4][2], int kb, bf16x8 (&kfn)[4][2], int kbn) {
    loadK(kfn, kbn);                       // prefetch next K tile
    bf16x8 vb[2][4];                       // V^T frags for THIS tile, issued early
    #pragma unroll
    for (int ks = 0; ks < 2; ks++)
    #pragma unroll
    for (int t = 0; t < 4; t++)
      vb[ks][t] = *(const bf16x8*)(VT + swz(h * 64 + t * 16 + lr,
                                            b * Nn + kb + ks * 32 + lg * 8, Mrows));
    // S = Q K^T
    f32x4 accs[2][4] = {};
    #pragma unroll
    for (int sub = 0; sub < 4; sub++) {
      #pragma unroll
      for (int qi = 0; qi < 2; qi++) {
        accs[qi][sub] = mfma16(aq[qi][0], kf[sub][0], accs[qi][sub]);
        accs[qi][sub] = mfma16(aq[qi][1], kf[sub][1], accs[qi][sub]);
      }
    }
    // additive mask
    float mk[4];
    #pragma unroll
    for (int sub = 0; sub < 4; sub++) mk[sub] = maskF[kb + sub * 16 + lr];
    float sv[2][4][4];
    #pragma unroll
    for (int qi = 0; qi < 2; qi++)
    #pragma unroll
    for (int sub = 0; sub < 4; sub++)
    #pragma unroll
    for (int r = 0; r < 4; r++)
      sv[qi][sub][r] = accs[qi][sub][r] * scale + mk[sub];
    // diagonal always attendable -- only in the tile containing this wave's rows
    if (kb == (q0 & ~63)) {
      #pragma unroll
      for (int qi = 0; qi < 2; qi++)
      #pragma unroll
      for (int sub = 0; sub < 4; sub++) {
        int key = kb + sub * 16 + lr;
        #pragma unroll
        for (int r = 0; r < 4; r++) {
          int qrow = q0 + qi * 16 + lg * 4 + r;
          if (key == qrow) sv[qi][sub][r] = accs[qi][sub][r] * scale;
        }
      }
    }
    // defer-max: skip rescale unless some row max exceeds m_run + 8
    bool allok = true;
    float pmax[2][4];
    #pragma unroll
    for (int qi = 0; qi < 2; qi++)
    #pragma unroll
    for (int r = 0; r < 4; r++) {
      pmax[qi][r] = fmaxf(fmaxf(sv[qi][0][r], sv[qi][1][r]),
                          fmaxf(sv[qi][2][r], sv[qi][3][r]));
      allok = allok && (pmax[qi][r] <= m_run[qi][r] + 8.0f);
    }
    if (!__all(allok)) {
      #pragma unroll
      for (int qi = 0; qi < 2; qi++)
      #pragma unroll
      for (int r = 0; r < 4; r++) {
        float m = pmax[qi][r];
        #pragma unroll
        for (int off = 1; off < 16; off <<= 1) m = fmaxf(m, __shfl_xor(m, off));
        float mtot = fmaxf(m_run[qi][r], m);
        float alpha = __expf(m_run[qi][r] - mtot);
        l_run[qi][r] *= alpha;
        m_run[qi][r] = mtot;
        #pragma unroll
        for (int t = 0; t < 4; t++) acco[qi][t][r] *= alpha;
      }
    }
    // exps + P write (per-lane partial l sums; reduced in epilogue)
    #pragma unroll
    for (int qi = 0; qi < 2; qi++) {
      #pragma unroll
      for (int sub = 0; sub < 4; sub++)
      #pragma unroll
      for (int r = 0; r < 4; r++) {
        float e = __expf(sv[qi][sub][r] - m_run[qi][r]);
        l_run[qi][r] += e;
        Plds[w][qi * 16 + lg * 4 + r][sub * 16 + lr] = f2bf(e);
      }
    }
    // O += P @ V
    #pragma unroll
    for (int ks = 0; ks < 2; ks++) {
      bf16x8 pa0 = *(const bf16x8*)(&Plds[w][lr][ks * 32 + lg * 8]);
      bf16x8 pa1 = *(const bf16x8*)(&Plds[w][16 + lr][ks * 32 + lg * 8]);
      #pragma unroll
      for (int t = 0; t < 4; t++) {
        acco[0][t] = mfma16(pa0, vb[ks][t], acco[0][t]);
        acco[1][t] = mfma16(pa1, vb[ks][t], acco[1][t]);
      }
    }
  };

  bf16x8 kfA[4][2], kfB[4][2];
  loadK(kfA, 0);
  for (int kb = 0; kb < Nn; kb += 128) {
    int n1 = kb + 64;
    int n2 = (kb + 128 < Nn) ? (kb + 128) : 0;
    process(kfA, kb, kfB, n1);
    process(kfB, n1, kfA, n2);
  }

  // epilogue: reduce l across the 16-lane group, divide, write bf16 O (swz)
  #pragma unroll
  for (int qi = 0; qi < 2; qi++)
  #pragma unroll
  for (int r = 0; r < 4; r++) {
    float lsum = l_run[qi][r];
    #pragma unroll
    for (int off = 1; off < 16; off <<= 1) lsum += __shfl_xor(lsum, off);
    l_run[qi][r] = lsum;
  }
  #pragma unroll
  for (int qi = 0; qi < 2; qi++)
  #pragma unroll
  for (int t = 0; t < 4; t++)
  #pragma unroll
  for (int r = 0; r < 4; r++) {
    int q = b * Nn + q0 + qi * 16 + lg * 4 + r;
    Obf[swz(q, h * 64 + t * 16 + lr, Dd)] = f2bf(acco[qi][t][r] / l_run[qi][r]);
  }
}

// ---------------------------------------------------------------------------
extern "C" void kernel_launch(void* const* d_in, const int* in_sizes, int n_in,
                              void* d_out, int out_size, void* d_ws, size_t ws_size,
                              hipStream_t stream) {
  const float* X    = (const float*)d_in[0];
  const int*   train= (const int*)d_in[1];
  const int*   batch= (const int*)d_in[2];
  const float* Wq   = (const float*)d_in[3];
  const float* bq   = (const float*)d_in[4];
  const float* Wk   = (const float*)d_in[5];
  const float* bk   = (const float*)d_in[6];
  const float* Wv   = (const float*)d_in[7];
  const float* bv   = (const float*)d_in[8];
  const float* Wmix = (const float*)d_in[9];
  const float* bmix = (const float*)d_in[10];
  const float* ln0s = (const float*)d_in[11];
  const float* ln0b = (const float*)d_in[12];
  const float* ln1s = (const float*)d_in[13];
  const float* ln1b = (const float*)d_in[14];
  const float* wi0  = (const float*)d_in[15];
  const float* wi1  = (const float*)d_in[16];
  const float* wo   = (const float*)d_in[17];
  float* out = (float*)d_out;

  char* ws = (char*)d_ws;
  size_t off = 0;
  auto alloc = [&](size_t bytes) {
    off = (off + 255) & ~(size_t)255;
    void* p = ws + off; off += bytes; return p;
  };
  short* Xbf   = (short*)alloc((size_t)Mrows * Dd * 2);
  short* Xnbf  = (short*)alloc((size_t)Mrows * Dd * 2);
  short* Qbf   = (short*)alloc((size_t)Mrows * Dd * 2);
  short* Kbf   = (short*)alloc((size_t)Mrows * Dd * 2);
  short* VTg   = (short*)alloc((size_t)Dd * Mrows * 2);   // V^T swz [Dd][Mrows]
  short* Obf   = (short*)alloc((size_t)Mrows * Dd * 2);
  short* x1bf  = (short*)alloc((size_t)Mrows * Dd * 2);
  short* Gbf   = (short*)alloc((size_t)Mrows * FFd * 2);  // gelu(x1@wi0)
  short* FFbf  = (short*)alloc((size_t)Mrows * FFd * 2);
  short* WqT   = (short*)alloc((size_t)Dd * Dd * 2);
  short* WkT   = (short*)alloc((size_t)Dd * Dd * 2);
  short* WvT   = (short*)alloc((size_t)Dd * Dd * 2);
  short* WmixT = (short*)alloc((size_t)Dd * Dd * 2);
  short* wi0T  = (short*)alloc((size_t)FFd * Dd * 2);
  short* wi1T  = (short*)alloc((size_t)FFd * Dd * 2);
  short* woT   = (short*)alloc((size_t)Dd * FFd * 2);
  float* Hcf   = (float*)alloc((size_t)Mrows * Dd * 4);
  char*  allowC= (char*)alloc((size_t)Mrows);

  dim3 blk(256);
  // weight transposes to bf16 swz[N][K] (batched)
  TJobs tj4; tj4.j[0] = {Wq, WqT}; tj4.j[1] = {Wk, WkT};
  tj4.j[2] = {Wv, WvT}; tj4.j[3] = {Wmix, WmixT};
  k_transpose_bf16<<<dim3(Dd / 32, Dd / 32, 4), blk, 0, stream>>>(tj4, Dd, Dd);
  TJobs tj2; tj2.j[0] = {wi0, wi0T}; tj2.j[1] = {wi1, wi1T};
  tj2.j[2] = {wi0, wi0T}; tj2.j[3] = {wi1, wi1T};
  k_transpose_bf16<<<dim3(FFd / 32, Dd / 32, 2), blk, 0, stream>>>(tj2, Dd, FFd);
  TJobs tj1; tj1.j[0] = {wo, woT}; tj1.j[1] = {wo, woT};
  tj1.j[2] = {wo, woT}; tj1.j[3] = {wo, woT};
  k_transpose_bf16<<<dim3(Dd / 32, FFd / 32, 1), blk, 0, stream>>>(tj1, FFd, Dd);

  // mask
  k_mask<<<Mrows / 256, blk, 0, stream>>>(train, batch, allowC);

  // LN0 (writes Xn bf16 and raw X bf16) -- one row per wave
  k_layernorm<true><<<Mrows / 4, blk, 0, stream>>>(X, ln0s, ln0b, Xnbf, Xbf);

  // Q (bf16, also serves as residual), K  -- BK=64
  k_gemm128<64, 64, 1, 0, false, true, 0><<<dim3(Dd / 64, Mrows / 128), blk, 0, stream>>>(
      Xnbf, WqT, bq, nullptr, nullptr, nullptr, nullptr, Qbf, Mrows, Dd, Dd);
  k_gemm128<64, 64, 1, 0, false, true, 0><<<dim3(Dd / 64, Mrows / 128), blk, 0, stream>>>(
      Xbf, WkT, bk, nullptr, nullptr, nullptr, nullptr, Kbf, Mrows, Dd, Dd);
  // V^T = WvT @ Xbf^T  (bias indexed by output ROW = V column)
  k_gemm128<64, 64, 2, 0, false, true, 0><<<dim3(Mrows / 64, Dd / 128), blk, 0, stream>>>(
      WvT, Xbf, bv, nullptr, nullptr, nullptr, nullptr, VTg, Dd, Mrows, Dd);

  // attention (barrier-free, 128 q-rows per block, XCD-pinned per head)
  k_attention<<<Bb * Hh * (Nn / 128), blk, 0, stream>>>(Qbf, Kbf, VTg, allowC, Obf);

  // Hc = O @ Wmix + bmix + Q (residual from bf16 Qbf)
  k_gemm128<64, 64, 1, 2, true, false, 0><<<dim3(Dd / 64, Mrows / 128), blk, 0, stream>>>(
      Obf, WmixT, bmix, nullptr, Qbf, nullptr, Hcf, nullptr, Mrows, Dd, Dd);

  // LN1
  k_layernorm<false><<<Mrows / 4, blk, 0, stream>>>(Hcf, ln1s, ln1b, x1bf, nullptr);

  // FF part 1: G = gelu(x1 @ wi0)
  k_gemm128<128, 32, 0, 0, false, true, 1><<<dim3(FFd / 128, Mrows / 128), blk, 0, stream>>>(
      x1bf, wi0T, nullptr, nullptr, nullptr, nullptr, nullptr, Gbf, Mrows, FFd, Dd);
  // FF part 2: FF = (x1 @ wi1) * G
  k_gemm128<128, 32, 0, 0, false, true, 2><<<dim3(FFd / 128, Mrows / 128), blk, 0, stream>>>(
      x1bf, wi1T, nullptr, nullptr, nullptr, Gbf, nullptr, FFbf, Mrows, FFd, Dd);

  // out = Hc + FF @ wo  -- BK=64
  k_gemm128<64, 64, 0, 1, true, false, 0><<<dim3(Dd / 64, Mrows / 128), blk, 0, stream>>>(
      FFbf, woT, nullptr, Hcf, nullptr, nullptr, out, nullptr, Mrows, Dd, FFd);
}